// Round 5
// baseline (10615.519 us; speedup 1.0000x reference)
//
#include <hip/hip_runtime.h>
#include <math.h>

#define BATCH 64
#define SEQ   512
#define DIMK  1024
#define HID   1024
#define NWG   256         // 128 col-groups x 2 batch-halves
#define BLK   512
#define HPW   8           // hidden columns per WG
#define NCOL  32          // 4 gates * HPW
#define BPAD  1032        // LDS col stride (1024 + 8)
#define BH    (BATCH * HID)
#define ROWS  32          // batch rows per WG
#define SCRW  (NCOL + 4)

typedef _Float16 h8  __attribute__((ext_vector_type(8)));
typedef float    f4  __attribute__((ext_vector_type(4)));
typedef float    fv4 __attribute__((ext_vector_type(4)));
typedef unsigned long long u64;

#define MFMA(a, b, c) __builtin_amdgcn_mfma_f32_16x16x32_f16(a, b, c, 0, 0, 0)

// Fast gate math: native exp2-based exp + v_rcp. Saturates correctly at +-inf.
__device__ __forceinline__ float fsig(float z){
    return __builtin_amdgcn_rcpf(1.f + __expf(-z));
}
__device__ __forceinline__ float ftanh(float z){
    return 1.f - 2.f * __builtin_amdgcn_rcpf(1.f + __expf(2.f * z));
}

// Stage 32 columns (4 gates x 8 hidden) of four fp32 matrices into LDS as fp16 hi+lo planes.
__device__ __forceinline__ void stage32(const float* const M[4], int hb,
                                        _Float16* BlH, _Float16* BlL){
    int jj = threadIdx.x & 7;
    int kk = threadIdx.x >> 3;          // 0..63
    #pragma unroll
    for (int g = 0; g < 4; ++g){
        const float* Mg = M[g];
        #pragma unroll
        for (int it = 0; it < 16; ++it){
            int k = kk + 64 * it;
            float v = Mg[(long)k * HID + hb + jj];
            _Float16 hi = (_Float16)v;
            _Float16 lo = (_Float16)(v - (float)hi);
            BlH[(g * HPW + jj) * BPAD + k] = hi;
            BlL[(g * HPW + jj) * BPAD + k] = lo;
        }
    }
}

__global__ void __launch_bounds__(BLK, 2)
lstm_kernel(const float* x,
            const float* wf, const float* wi, const float* wo, const float* wc,
            const float* uf, const float* ui, const float* uo, const float* uc,
            const float* bfp, const float* bip, const float* bop, const float* bcp,
            float* out, unsigned* flags, _Float16* hbuf)
{
    __shared__ _Float16 BlH[NCOL * BPAD];          // U_hi (dead as LDS after B-reg load)
    __shared__ _Float16 BlL[NCOL * BPAD];          // U_lo
    __shared__ float    scr[4][ROWS][SCRW];        // 4-way k-split reduction

    const int tid  = threadIdx.x;
    const int lane = tid & 63;
    const int wave = tid >> 6;
    const int mt   = wave & 1;          // m-tile (16 rows of the 32-row slice)
    const int ks   = wave >> 1;         // k-quarter (256)
    const int cg   = blockIdx.x >> 1;   // col-group
    const int bh   = blockIdx.x & 1;    // batch half
    const int hb   = cg * HPW;

    const int arow = mt * 16 + (lane & 15);      // local row 0..31
    const int grow = bh * ROWS + arow;           // global batch row
    const int kb   = ks * 256 + ((lane >> 4) * 8);
    const int bcol = lane & 15;

    const float* Ws[4] = {wf, wi, wo, wc};
    const float* Us[4] = {uf, ui, uo, uc};

    // ---- Phase 0: gx = x0 @ W + b ----
    stage32(Ws, hb, BlH, BlL);
    __syncthreads();

    f4 acc0 = {0.f,0.f,0.f,0.f}, acc1 = {0.f,0.f,0.f,0.f};
    {
        const float* Ar = x + (long)grow * (SEQ * DIMK);
        #pragma unroll
        for (int i = 0; i < 8; ++i){
            int k = kb + i * 32;
            fv4 xa = *(const fv4*)(Ar + k);
            fv4 xb = *(const fv4*)(Ar + k + 4);
            h8 xhi, xlo;
            #pragma unroll
            for (int j = 0; j < 4; ++j){
                xhi[j]   = (_Float16)xa[j];  xlo[j]   = (_Float16)(xa[j] - (float)xhi[j]);
                xhi[4+j] = (_Float16)xb[j];  xlo[4+j] = (_Float16)(xb[j] - (float)xhi[4+j]);
            }
            h8 b0h = *(const h8*)&BlH[ bcol       * BPAD + k];
            h8 b1h = *(const h8*)&BlH[(16 + bcol) * BPAD + k];
            h8 b0l = *(const h8*)&BlL[ bcol       * BPAD + k];
            h8 b1l = *(const h8*)&BlL[(16 + bcol) * BPAD + k];
            acc0 = MFMA(xhi, b0h, acc0); acc0 = MFMA(xlo, b0h, acc0); acc0 = MFMA(xhi, b0l, acc0);
            acc1 = MFMA(xhi, b1h, acc1); acc1 = MFMA(xlo, b1h, acc1); acc1 = MFMA(xhi, b1l, acc1);
        }
    }
    {
        int r0 = mt * 16 + ((lane >> 4) << 2);
        #pragma unroll
        for (int r = 0; r < 4; ++r){
            scr[ks][r0 + r][bcol]      = acc0[r];
            scr[ks][r0 + r][16 + bcol] = acc1[r];
        }
    }
    __syncthreads();

    const int eb = tid >> 3;            // local batch row (waves 0-3)
    const int ej = tid & 7;             // hidden col within WG slice
    float gx0 = 0.f, gx1 = 0.f, gx2 = 0.f, gx3 = 0.f;
    if (wave < 4){
        gx0 = scr[0][eb][ 0+ej] + scr[1][eb][ 0+ej] + scr[2][eb][ 0+ej] + scr[3][eb][ 0+ej] + bfp[hb + ej];
        gx1 = scr[0][eb][ 8+ej] + scr[1][eb][ 8+ej] + scr[2][eb][ 8+ej] + scr[3][eb][ 8+ej] + bip[hb + ej];
        gx2 = scr[0][eb][16+ej] + scr[1][eb][16+ej] + scr[2][eb][16+ej] + scr[3][eb][16+ej] + bop[hb + ej];
        gx3 = scr[0][eb][24+ej] + scr[1][eb][24+ej] + scr[2][eb][24+ej] + scr[3][eb][24+ej] + bcp[hb + ej];
    }
    __syncthreads();
    stage32(Us, hb, BlH, BlL);          // stage U once
    __syncthreads();

    // ---- U fragments into registers: invariant across all 512 steps ----
    h8 Bh0[8], Bh1[8], Bl0[8], Bl1[8];
    #pragma unroll
    for (int i = 0; i < 8; ++i){
        int k = kb + i * 32;
        Bh0[i] = *(const h8*)&BlH[ bcol       * BPAD + k];
        Bh1[i] = *(const h8*)&BlH[(16 + bcol) * BPAD + k];
        Bl0[i] = *(const h8*)&BlL[ bcol       * BPAD + k];
        Bl1[i] = *(const h8*)&BlL[(16 + bcol) * BPAD + k];
    }

    // Flags: one u32 per WG on its own 128-B line (round-2 spread layout).
    unsigned* pubp = flags + ((unsigned)blockIdx.x << 5);

    // Kill stale L1/L2 lines (hbuf from a previous graph replay) before first plain loads.
    __builtin_amdgcn_fence(__ATOMIC_ACQUIRE, "agent");

    // ---- Recurrence: 512 steps ----
    float cstate = 0.f;
    const int  orow  = bh * ROWS + eb;
    const long obase = (long)orow * (SEQ * HID) + hb + ej;

    for (int t = 0; t < SEQ; ++t){
        const _Float16* hcH = hbuf + (t & 1) * (2 * BH);
        const _Float16* hcL = hcH + BH;

        // Plain cached loads: first toucher per XCD fills L2 from LLC; the other
        // co-located WGs hit L2. Freshness guaranteed by the per-step acquire fence.
        h8 aH[8], aL[8];
        const _Float16* ApH = hcH + grow * HID + kb;
        const _Float16* ApL = hcL + grow * HID + kb;
        #pragma unroll
        for (int i = 0; i < 8; ++i) aH[i] = *(const h8*)(ApH + i * 32);
        #pragma unroll
        for (int i = 0; i < 8; ++i) aL[i] = *(const h8*)(ApL + i * 32);

        f4 z0 = {0.f,0.f,0.f,0.f}, z1 = {0.f,0.f,0.f,0.f};
        #pragma unroll
        for (int i = 0; i < 8; ++i){
            z0 = MFMA(aH[i], Bh0[i], z0); z0 = MFMA(aL[i], Bh0[i], z0); z0 = MFMA(aH[i], Bl0[i], z0);
            z1 = MFMA(aH[i], Bh1[i], z1); z1 = MFMA(aL[i], Bh1[i], z1); z1 = MFMA(aH[i], Bl1[i], z1);
        }
        {
            int r0 = mt * 16 + ((lane >> 4) << 2);
            #pragma unroll
            for (int r = 0; r < 4; ++r){
                scr[ks][r0 + r][bcol]      = z0[r];
                scr[ks][r0 + r][16 + bcol] = z1[r];
            }
        }
        __syncthreads();                 // sync 1: scr exchange

        if (wave < 4){
            float zf = gx0 + scr[0][eb][ 0+ej] + scr[1][eb][ 0+ej] + scr[2][eb][ 0+ej] + scr[3][eb][ 0+ej];
            float zi = gx1 + scr[0][eb][ 8+ej] + scr[1][eb][ 8+ej] + scr[2][eb][ 8+ej] + scr[3][eb][ 8+ej];
            float zo = gx2 + scr[0][eb][16+ej] + scr[1][eb][16+ej] + scr[2][eb][16+ej] + scr[3][eb][16+ej];
            float zc = gx3 + scr[0][eb][24+ej] + scr[1][eb][24+ej] + scr[2][eb][24+ej] + scr[3][eb][24+ej];
            float f  = fsig(zf);
            float ii = fsig(zi);
            float o  = fsig(zo);
            float ch = ftanh(zc);
            cstate   = f * cstate + ii * ch;
            float hv = o * ftanh(cstate);

            if (t < SEQ - 1){
                _Float16* hnH = hbuf + ((t + 1) & 1) * (2 * BH);
                _Float16* hnL = hnH + BH;
                _Float16 hhi = (_Float16)hv;
                _Float16 hlo = (_Float16)(hv - (float)hhi);
                unsigned uhi = (unsigned short)__builtin_bit_cast(unsigned short, hhi);
                unsigned ulo = (unsigned short)__builtin_bit_cast(unsigned short, hlo);
                unsigned phi = (unsigned)__shfl_xor((int)uhi, 1);
                unsigned plo = (unsigned)__shfl_xor((int)ulo, 1);
                if (!(ej & 1)){          // even col: store packed dword (this + partner)
                    int widx = (orow * HID + hb + ej) >> 1;
                    __hip_atomic_store((unsigned*)hnH + widx, uhi | (phi << 16),
                                       __ATOMIC_RELAXED, __HIP_MEMORY_SCOPE_AGENT);
                    __hip_atomic_store((unsigned*)hnL + widx, ulo | (plo << 16),
                                       __ATOMIC_RELAXED, __HIP_MEMORY_SCOPE_AGENT);
                }
            }
            // out via agent atomic: keeps L2 free of dirty lines (fence-safe), bypasses cache.
            __hip_atomic_store(out + obase + (long)t * HID, hv,
                               __ATOMIC_RELAXED, __HIP_MEMORY_SCOPE_AGENT);
        }
        __syncthreads();                 // sync 2: compiler drains vmcnt(0) for every wave
                                         // => all h/out stores LLC-acked before anyone proceeds

        if (t < SEQ - 1){
            if (tid == 0)
                __hip_atomic_store(pubp, (unsigned)(t + 1),
                                   __ATOMIC_RELAXED, __HIP_MEMORY_SCOPE_AGENT);
            if (tid < 128){              // poll only same-half WGs, one spread line each
                const unsigned* fp = flags + ((((unsigned)tid << 1) | (unsigned)bh) << 5);
                while (__hip_atomic_load(fp, __ATOMIC_RELAXED, __HIP_MEMORY_SCOPE_AGENT)
                       < (unsigned)(t + 1))
                    __builtin_amdgcn_s_sleep(1);
            }
            __syncthreads();             // sync 3: release
            // Acquire: every wave invalidates stale L1/L2 before its next h loads.
            __builtin_amdgcn_fence(__ATOMIC_ACQUIRE, "agent");
        }
    }
}

extern "C" void kernel_launch(void* const* d_in, const int* in_sizes, int n_in,
                              void* d_out, int out_size, void* d_ws, size_t ws_size,
                              hipStream_t stream)
{
    const float* x  = (const float*)d_in[0];
    const float* wf = (const float*)d_in[1];
    const float* wi = (const float*)d_in[2];
    const float* wo = (const float*)d_in[3];
    const float* wc = (const float*)d_in[4];
    const float* uf = (const float*)d_in[5];
    const float* ui = (const float*)d_in[6];
    const float* uo = (const float*)d_in[7];
    const float* uc = (const float*)d_in[8];
    const float* bf = (const float*)d_in[9];
    const float* bi = (const float*)d_in[10];
    const float* bo = (const float*)d_in[11];
    const float* bc = (const float*)d_in[12];
    float* out = (float*)d_out;

    unsigned*  flags = (unsigned*)d_ws;                       // 256 x 128-B flag lines
    _Float16*  hbuf  = (_Float16*)((char*)d_ws + 32768);      // h ping-pong (hi+lo planes)

    // zero flags + both h ping-pong buffers; h0 = 0, epoch 0 == "h(0) ready"
    hipMemsetAsync(d_ws, 0, 32768 + (size_t)2 * 2 * BH * sizeof(_Float16), stream);

    void* args[] = { &x, &wf, &wi, &wo, &wc, &uf, &ui, &uo, &uc,
                     &bf, &bi, &bo, &bc, &out, &flags, &hbuf };
    hipLaunchCooperativeKernel((void*)lstm_kernel, dim3(NWG), dim3(BLK), args, 0, stream);
}

// Round 7
// 5093.162 us; speedup vs baseline: 2.0843x; 2.0843x over previous
//
#include <hip/hip_runtime.h>
#include <math.h>

#define BATCH 64
#define SEQ   512
#define DIMK  1024
#define HID   1024
#define NWG   256         // 128 col-groups x 2 batch-halves
#define BLK   512
#define HPW   8           // hidden columns per WG
#define NCOL  32          // 4 gates * HPW
#define BPAD  1032        // LDS col stride (1024 + 8)
#define BH    (BATCH * HID)
#define ROWS  32          // batch rows per WG
#define SCRW  (NCOL + 4)

typedef _Float16 h8  __attribute__((ext_vector_type(8)));
typedef float    f4  __attribute__((ext_vector_type(4)));
typedef float    fv4 __attribute__((ext_vector_type(4)));
typedef unsigned long long u64;

#define MFMA(a, b, c) __builtin_amdgcn_mfma_f32_16x16x32_f16(a, b, c, 0, 0, 0)

// 16-B fragment load, LLC-coherent, bypasses L1/L2 — no fences needed.
__device__ __forceinline__ h8 ldh8_llc(const _Float16* p){
    union { u64 q[2]; h8 v; } r;
    const u64* q = (const u64*)p;
    r.q[0] = __hip_atomic_load((u64*)(q + 0), __ATOMIC_RELAXED, __HIP_MEMORY_SCOPE_AGENT);
    r.q[1] = __hip_atomic_load((u64*)(q + 1), __ATOMIC_RELAXED, __HIP_MEMORY_SCOPE_AGENT);
    return r.v;
}

// Fast gate math: native exp2-based exp + v_rcp. Saturates correctly at +-inf.
__device__ __forceinline__ float fsig(float z){
    return __builtin_amdgcn_rcpf(1.f + __expf(-z));
}
__device__ __forceinline__ float ftanh(float z){
    return 1.f - 2.f * __builtin_amdgcn_rcpf(1.f + __expf(2.f * z));
}

// Stage 32 columns (4 gates x 8 hidden) of four fp32 matrices into LDS as fp16 hi+lo planes.
__device__ __forceinline__ void stage32(const float* const M[4], int hb,
                                        _Float16* BlH, _Float16* BlL){
    int jj = threadIdx.x & 7;
    int kk = threadIdx.x >> 3;          // 0..63
    #pragma unroll
    for (int g = 0; g < 4; ++g){
        const float* Mg = M[g];
        #pragma unroll
        for (int it = 0; it < 16; ++it){
            int k = kk + 64 * it;
            float v = Mg[(long)k * HID + hb + jj];
            _Float16 hi = (_Float16)v;
            _Float16 lo = (_Float16)(v - (float)hi);
            BlH[(g * HPW + jj) * BPAD + k] = hi;
            BlL[(g * HPW + jj) * BPAD + k] = lo;
        }
    }
}

__global__ void __launch_bounds__(BLK, 2)
lstm_kernel(const float* x,
            const float* wf, const float* wi, const float* wo, const float* wc,
            const float* uf, const float* ui, const float* uo, const float* uc,
            const float* bfp, const float* bip, const float* bop, const float* bcp,
            float* out, unsigned* flags, _Float16* hbuf)
{
    __shared__ _Float16 BlH[NCOL * BPAD];          // U_hi (dead as LDS after B-reg load)
    __shared__ _Float16 BlL[NCOL * BPAD];          // U_lo
    __shared__ float    scr[4][ROWS][SCRW];        // 4-way k-split reduction

    const int tid  = threadIdx.x;
    const int lane = tid & 63;
    const int wave = tid >> 6;
    const int mt   = wave & 1;          // m-tile (16 rows of the 32-row slice)
    const int ks   = wave >> 1;         // k-quarter (256)
    const int cg   = blockIdx.x >> 1;   // col-group
    const int bh   = blockIdx.x & 1;    // batch half
    const int hb   = cg * HPW;

    const int arow = mt * 16 + (lane & 15);      // local row 0..31
    const int grow = bh * ROWS + arow;           // global batch row
    const int kb   = ks * 256 + ((lane >> 4) * 8);
    const int bcol = lane & 15;

    const float* Ws[4] = {wf, wi, wo, wc};
    const float* Us[4] = {uf, ui, uo, uc};

    // ---- Phase 0: gx = x0 @ W + b ----
    stage32(Ws, hb, BlH, BlL);
    __syncthreads();

    f4 acc0 = {0.f,0.f,0.f,0.f}, acc1 = {0.f,0.f,0.f,0.f};
    {
        const float* Ar = x + (long)grow * (SEQ * DIMK);
        #pragma unroll
        for (int i = 0; i < 8; ++i){
            int k = kb + i * 32;
            fv4 xa = *(const fv4*)(Ar + k);
            fv4 xb = *(const fv4*)(Ar + k + 4);
            h8 xhi, xlo;
            #pragma unroll
            for (int j = 0; j < 4; ++j){
                xhi[j]   = (_Float16)xa[j];  xlo[j]   = (_Float16)(xa[j] - (float)xhi[j]);
                xhi[4+j] = (_Float16)xb[j];  xlo[4+j] = (_Float16)(xb[j] - (float)xhi[4+j]);
            }
            h8 b0h = *(const h8*)&BlH[ bcol       * BPAD + k];
            h8 b1h = *(const h8*)&BlH[(16 + bcol) * BPAD + k];
            h8 b0l = *(const h8*)&BlL[ bcol       * BPAD + k];
            h8 b1l = *(const h8*)&BlL[(16 + bcol) * BPAD + k];
            acc0 = MFMA(xhi, b0h, acc0); acc0 = MFMA(xlo, b0h, acc0); acc0 = MFMA(xhi, b0l, acc0);
            acc1 = MFMA(xhi, b1h, acc1); acc1 = MFMA(xlo, b1h, acc1); acc1 = MFMA(xhi, b1l, acc1);
        }
    }
    {
        int r0 = mt * 16 + ((lane >> 4) << 2);
        #pragma unroll
        for (int r = 0; r < 4; ++r){
            scr[ks][r0 + r][bcol]      = acc0[r];
            scr[ks][r0 + r][16 + bcol] = acc1[r];
        }
    }
    __syncthreads();

    const int eb = tid >> 3;            // local batch row (waves 0-3)
    const int ej = tid & 7;             // hidden col within WG slice
    float gx0 = 0.f, gx1 = 0.f, gx2 = 0.f, gx3 = 0.f;
    if (wave < 4){
        gx0 = scr[0][eb][ 0+ej] + scr[1][eb][ 0+ej] + scr[2][eb][ 0+ej] + scr[3][eb][ 0+ej] + bfp[hb + ej];
        gx1 = scr[0][eb][ 8+ej] + scr[1][eb][ 8+ej] + scr[2][eb][ 8+ej] + scr[3][eb][ 8+ej] + bip[hb + ej];
        gx2 = scr[0][eb][16+ej] + scr[1][eb][16+ej] + scr[2][eb][16+ej] + scr[3][eb][16+ej] + bop[hb + ej];
        gx3 = scr[0][eb][24+ej] + scr[1][eb][24+ej] + scr[2][eb][24+ej] + scr[3][eb][24+ej] + bcp[hb + ej];
    }
    stage32(Us, hb, BlH, BlL);          // stage U once (BlH/BlL reads all done pre-sync)
    __syncthreads();

    // ---- U fragments into registers: invariant across all 512 steps ----
    h8 Bh0[8], Bh1[8], Bl0[8], Bl1[8];
    #pragma unroll
    for (int i = 0; i < 8; ++i){
        int k = kb + i * 32;
        Bh0[i] = *(const h8*)&BlH[ bcol       * BPAD + k];
        Bh1[i] = *(const h8*)&BlH[(16 + bcol) * BPAD + k];
        Bl0[i] = *(const h8*)&BlL[ bcol       * BPAD + k];
        Bl1[i] = *(const h8*)&BlL[(16 + bcol) * BPAD + k];
    }

    // Flag layout — ALL inside the proven 32-KB region (hbuf stays at +32768):
    //   member[bid]  : flags + bid*16        (64-B stride, 256 lines, bytes 0..16383)
    //   group[bh][g] : flags + 4096 + (bh*8+g)*32  (128-B stride, bytes 16384..18431)
    const int      mIdx  = blockIdx.x >> 1;        // member index within half, 0..127
    unsigned*      myMem = flags + ((unsigned)blockIdx.x << 4);
    const bool     isComb = (mIdx & 15) == 0;      // combiner for members mIdx..mIdx+15

    // ---- Recurrence: 512 steps ----
    float cstate = 0.f;
    const int  orow  = bh * ROWS + eb;
    const long obase = (long)orow * (SEQ * HID) + hb + ej;

    for (int t = 0; t < SEQ; ++t){
        const _Float16* hcH = hbuf + (t & 1) * (2 * BH);
        const _Float16* hcL = hcH + BH;

        h8 aH[8], aL[8];
        const _Float16* ApH = hcH + grow * HID + kb;
        const _Float16* ApL = hcL + grow * HID + kb;
        #pragma unroll
        for (int i = 0; i < 8; ++i) aH[i] = ldh8_llc(ApH + i * 32);
        #pragma unroll
        for (int i = 0; i < 8; ++i) aL[i] = ldh8_llc(ApL + i * 32);

        f4 z0 = {0.f,0.f,0.f,0.f}, z1 = {0.f,0.f,0.f,0.f};
        #pragma unroll
        for (int i = 0; i < 8; ++i){
            z0 = MFMA(aH[i], Bh0[i], z0); z0 = MFMA(aL[i], Bh0[i], z0); z0 = MFMA(aH[i], Bl0[i], z0);
            z1 = MFMA(aH[i], Bh1[i], z1); z1 = MFMA(aL[i], Bh1[i], z1); z1 = MFMA(aH[i], Bl1[i], z1);
        }
        {
            int r0 = mt * 16 + ((lane >> 4) << 2);
            #pragma unroll
            for (int r = 0; r < 4; ++r){
                scr[ks][r0 + r][bcol]      = z0[r];
                scr[ks][r0 + r][16 + bcol] = z1[r];
            }
        }
        __syncthreads();                 // sync 1: scr exchange

        if (wave < 4){
            float zf = gx0 + scr[0][eb][ 0+ej] + scr[1][eb][ 0+ej] + scr[2][eb][ 0+ej] + scr[3][eb][ 0+ej];
            float zi = gx1 + scr[0][eb][ 8+ej] + scr[1][eb][ 8+ej] + scr[2][eb][ 8+ej] + scr[3][eb][ 8+ej];
            float zo = gx2 + scr[0][eb][16+ej] + scr[1][eb][16+ej] + scr[2][eb][16+ej] + scr[3][eb][16+ej];
            float zc = gx3 + scr[0][eb][24+ej] + scr[1][eb][24+ej] + scr[2][eb][24+ej] + scr[3][eb][24+ej];
            float f  = fsig(zf);
            float ii = fsig(zi);
            float o  = fsig(zo);
            float ch = ftanh(zc);
            cstate   = f * cstate + ii * ch;
            float hv = o * ftanh(cstate);

            if (t < SEQ - 1){
                _Float16* hnH = hbuf + ((t + 1) & 1) * (2 * BH);
                _Float16* hnL = hnH + BH;
                _Float16 hhi = (_Float16)hv;
                _Float16 hlo = (_Float16)(hv - (float)hhi);
                unsigned uhi = (unsigned short)__builtin_bit_cast(unsigned short, hhi);
                unsigned ulo = (unsigned short)__builtin_bit_cast(unsigned short, hlo);
                unsigned phi = (unsigned)__shfl_xor((int)uhi, 1);
                unsigned plo = (unsigned)__shfl_xor((int)ulo, 1);
                if (!(ej & 1)){          // even col: store packed dword (this + partner)
                    int widx = (orow * HID + hb + ej) >> 1;
                    __hip_atomic_store((unsigned*)hnH + widx, uhi | (phi << 16),
                                       __ATOMIC_RELAXED, __HIP_MEMORY_SCOPE_AGENT);
                    __hip_atomic_store((unsigned*)hnL + widx, ulo | (plo << 16),
                                       __ATOMIC_RELAXED, __HIP_MEMORY_SCOPE_AGENT);
                }
            }
            out[obase + (long)t * HID] = hv;   // plain store: L2 write-back, off the chain
        }
        __syncthreads();                 // sync 2: drains vmcnt for every wave
                                         // => h stores LLC-acked before arrive

        if (t < SEQ - 1){
            const unsigned tgt = (unsigned)(t + 1);
            if (wave == 0){
                // Arrive: own member line.
                if (lane == 0)
                    __hip_atomic_store(myMem, tgt, __ATOMIC_RELAXED, __HIP_MEMORY_SCOPE_AGENT);
                // Combine: 8 combiners/half each poll 16 member lines (single-reader lines).
                if (isComb){
                    const unsigned* mp = flags +
                        ((unsigned)((((mIdx + (lane & 15)) << 1) | bh)) << 4);
                    for (;;){
                        unsigned v = (lane < 16)
                            ? __hip_atomic_load(mp, __ATOMIC_RELAXED, __HIP_MEMORY_SCOPE_AGENT)
                            : ~0u;
                        if (__all((int)(v >= tgt))) break;
                        __builtin_amdgcn_s_sleep(1);
                    }
                    if (lane == 0)
                        __hip_atomic_store(flags + 4096 + ((unsigned)((bh << 3) + (mIdx >> 4)) << 5),
                                           tgt, __ATOMIC_RELAXED, __HIP_MEMORY_SCOPE_AGENT);
                }
                // Release-wait: poll only this half's 8 group lines.
                {
                    const unsigned* gp = flags + 4096 + ((unsigned)((bh << 3) + (lane & 7)) << 5);
                    for (;;){
                        unsigned v = (lane < 8)
                            ? __hip_atomic_load(gp, __ATOMIC_RELAXED, __HIP_MEMORY_SCOPE_AGENT)
                            : ~0u;
                        if (__all((int)(v >= tgt))) break;
                        __builtin_amdgcn_s_sleep(1);
                    }
                }
            }
            __syncthreads();             // sync 3: release the WG
        }
    }
}

extern "C" void kernel_launch(void* const* d_in, const int* in_sizes, int n_in,
                              void* d_out, int out_size, void* d_ws, size_t ws_size,
                              hipStream_t stream)
{
    const float* x  = (const float*)d_in[0];
    const float* wf = (const float*)d_in[1];
    const float* wi = (const float*)d_in[2];
    const float* wo = (const float*)d_in[3];
    const float* wc = (const float*)d_in[4];
    const float* uf = (const float*)d_in[5];
    const float* ui = (const float*)d_in[6];
    const float* uo = (const float*)d_in[7];
    const float* uc = (const float*)d_in[8];
    const float* bf = (const float*)d_in[9];
    const float* bi = (const float*)d_in[10];
    const float* bo = (const float*)d_in[11];
    const float* bc = (const float*)d_in[12];
    float* out = (float*)d_out;

    unsigned*  flags = (unsigned*)d_ws;                       // member+group flags, 32 KB
    _Float16*  hbuf  = (_Float16*)((char*)d_ws + 32768);      // h ping-pong (hi+lo planes)

    // zero flags + both h ping-pong buffers; h0 = 0, epoch 0 == "h(0) ready"
    // (557,056-byte footprint — identical to rounds 2-5, proven in-bounds)
    hipMemsetAsync(d_ws, 0, 32768 + (size_t)2 * 2 * BH * sizeof(_Float16), stream);

    void* args[] = { &x, &wf, &wi, &wo, &wc, &uf, &ui, &uo, &uc,
                     &bf, &bi, &bo, &bc, &out, &flags, &hbuf };
    hipLaunchCooperativeKernel((void*)lstm_kernel, dim3(NWG), dim3(BLK), args, 0, stream);
}

// Round 8
// 3372.723 us; speedup vs baseline: 3.1475x; 1.5101x over previous
//
#include <hip/hip_runtime.h>
#include <math.h>

#define BATCH 64
#define SEQ   512
#define DIMK  1024
#define HID   1024
#define NWG   256         // 128 col-groups x 2 batch-halves
#define BLK   512
#define HPW   8           // hidden columns per WG
#define NCOL  32          // 4 gates * HPW
#define BPAD  1032        // LDS col stride (1024 + 8)
#define BH    (BATCH * HID)
#define ROWS  32          // batch rows per WG
#define SCRW  (NCOL + 4)

typedef _Float16 h8  __attribute__((ext_vector_type(8)));
typedef float    f4  __attribute__((ext_vector_type(4)));
typedef float    fv4 __attribute__((ext_vector_type(4)));
typedef unsigned long long u64;

#define MFMA(a, b, c) __builtin_amdgcn_mfma_f32_16x16x32_f16(a, b, c, 0, 0, 0)

// 16-B fragment load, LLC-coherent, bypasses L1/L2 — no fences needed.
__device__ __forceinline__ h8 ldh8_llc(const _Float16* p){
    union { u64 q[2]; h8 v; } r;
    const u64* q = (const u64*)p;
    r.q[0] = __hip_atomic_load((u64*)(q + 0), __ATOMIC_RELAXED, __HIP_MEMORY_SCOPE_AGENT);
    r.q[1] = __hip_atomic_load((u64*)(q + 1), __ATOMIC_RELAXED, __HIP_MEMORY_SCOPE_AGENT);
    return r.v;
}

// Fast gate math: native exp2-based exp + v_rcp. Saturates correctly at +-inf.
__device__ __forceinline__ float fsig(float z){
    return __builtin_amdgcn_rcpf(1.f + __expf(-z));
}
__device__ __forceinline__ float ftanh(float z){
    return 1.f - 2.f * __builtin_amdgcn_rcpf(1.f + __expf(2.f * z));
}

// Stage 32 columns (4 gates x 8 hidden) of four fp32 matrices into LDS as fp16 hi+lo planes.
__device__ __forceinline__ void stage32(const float* const M[4], int hb,
                                        _Float16* BlH, _Float16* BlL){
    int jj = threadIdx.x & 7;
    int kk = threadIdx.x >> 3;          // 0..63
    #pragma unroll
    for (int g = 0; g < 4; ++g){
        const float* Mg = M[g];
        #pragma unroll
        for (int it = 0; it < 16; ++it){
            int k = kk + 64 * it;
            float v = Mg[(long)k * HID + hb + jj];
            _Float16 hi = (_Float16)v;
            _Float16 lo = (_Float16)(v - (float)hi);
            BlH[(g * HPW + jj) * BPAD + k] = hi;
            BlL[(g * HPW + jj) * BPAD + k] = lo;
        }
    }
}

__global__ void __launch_bounds__(BLK, 2)
lstm_kernel(const float* x,
            const float* wf, const float* wi, const float* wo, const float* wc,
            const float* uf, const float* ui, const float* uo, const float* uc,
            const float* bfp, const float* bip, const float* bop, const float* bcp,
            float* out, unsigned* flags, _Float16* hbuf)
{
    __shared__ _Float16 BlH[NCOL * BPAD];          // U_hi (dead as LDS after B-reg load)
    __shared__ _Float16 BlL[NCOL * BPAD];          // U_lo
    __shared__ float    scr[4][ROWS][SCRW];        // 4-way k-split reduction

    const int tid  = threadIdx.x;
    const int lane = tid & 63;
    const int wave = tid >> 6;
    const int mt   = wave & 1;          // m-tile (16 rows of the 32-row slice)
    const int ks   = wave >> 1;         // k-quarter (256)
    const int cg   = blockIdx.x >> 1;   // col-group
    const int bh   = blockIdx.x & 1;    // batch half
    const int hb   = cg * HPW;

    const int arow = mt * 16 + (lane & 15);      // local row 0..31
    const int grow = bh * ROWS + arow;           // global batch row
    const int kb   = ks * 256 + ((lane >> 4) * 8);
    const int bcol = lane & 15;

    const float* Ws[4] = {wf, wi, wo, wc};
    const float* Us[4] = {uf, ui, uo, uc};

    // ---- Phase 0: gx = x0 @ W + b (x fp32 -> hi/lo split, 3 passes, unchanged) ----
    stage32(Ws, hb, BlH, BlL);
    __syncthreads();

    f4 acc0 = {0.f,0.f,0.f,0.f}, acc1 = {0.f,0.f,0.f,0.f};
    {
        const float* Ar = x + (long)grow * (SEQ * DIMK);
        #pragma unroll
        for (int i = 0; i < 8; ++i){
            int k = kb + i * 32;
            fv4 xa = *(const fv4*)(Ar + k);
            fv4 xb = *(const fv4*)(Ar + k + 4);
            h8 xhi, xlo;
            #pragma unroll
            for (int j = 0; j < 4; ++j){
                xhi[j]   = (_Float16)xa[j];  xlo[j]   = (_Float16)(xa[j] - (float)xhi[j]);
                xhi[4+j] = (_Float16)xb[j];  xlo[4+j] = (_Float16)(xb[j] - (float)xhi[4+j]);
            }
            h8 b0h = *(const h8*)&BlH[ bcol       * BPAD + k];
            h8 b1h = *(const h8*)&BlH[(16 + bcol) * BPAD + k];
            h8 b0l = *(const h8*)&BlL[ bcol       * BPAD + k];
            h8 b1l = *(const h8*)&BlL[(16 + bcol) * BPAD + k];
            acc0 = MFMA(xhi, b0h, acc0); acc0 = MFMA(xlo, b0h, acc0); acc0 = MFMA(xhi, b0l, acc0);
            acc1 = MFMA(xhi, b1h, acc1); acc1 = MFMA(xlo, b1h, acc1); acc1 = MFMA(xhi, b1l, acc1);
        }
    }
    {
        int r0 = mt * 16 + ((lane >> 4) << 2);
        #pragma unroll
        for (int r = 0; r < 4; ++r){
            scr[ks][r0 + r][bcol]      = acc0[r];
            scr[ks][r0 + r][16 + bcol] = acc1[r];
        }
    }
    __syncthreads();

    const int eb = tid >> 3;            // local batch row (waves 0-3)
    const int ej = tid & 7;             // hidden col within WG slice
    float gx0 = 0.f, gx1 = 0.f, gx2 = 0.f, gx3 = 0.f;
    if (wave < 4){
        gx0 = scr[0][eb][ 0+ej] + scr[1][eb][ 0+ej] + scr[2][eb][ 0+ej] + scr[3][eb][ 0+ej] + bfp[hb + ej];
        gx1 = scr[0][eb][ 8+ej] + scr[1][eb][ 8+ej] + scr[2][eb][ 8+ej] + scr[3][eb][ 8+ej] + bip[hb + ej];
        gx2 = scr[0][eb][16+ej] + scr[1][eb][16+ej] + scr[2][eb][16+ej] + scr[3][eb][16+ej] + bop[hb + ej];
        gx3 = scr[0][eb][24+ej] + scr[1][eb][24+ej] + scr[2][eb][24+ej] + scr[3][eb][24+ej] + bcp[hb + ej];
    }
    stage32(Us, hb, BlH, BlL);          // stage U once (BlH/BlL reads all done pre-sync)
    __syncthreads();

    // ---- U fragments into registers: invariant across all 512 steps ----
    h8 Bh0[8], Bh1[8], Bl0[8], Bl1[8];
    #pragma unroll
    for (int i = 0; i < 8; ++i){
        int k = kb + i * 32;
        Bh0[i] = *(const h8*)&BlH[ bcol       * BPAD + k];
        Bh1[i] = *(const h8*)&BlH[(16 + bcol) * BPAD + k];
        Bl0[i] = *(const h8*)&BlL[ bcol       * BPAD + k];
        Bl1[i] = *(const h8*)&BlL[(16 + bcol) * BPAD + k];
    }

    // Flag layout — inside the 32-KB region (hbuf at +32768):
    //   member[bid]  : flags + bid*16        (64-B stride, 256 lines)
    //   group[bh][g] : flags + 4096 + (bh*8+g)*32  (128-B stride)
    const int      mIdx  = blockIdx.x >> 1;        // member index within half, 0..127
    unsigned*      myMem = flags + ((unsigned)blockIdx.x << 4);
    const bool     isComb = (mIdx & 15) == 0;      // combiner for members mIdx..mIdx+15

    // ---- Recurrence: 512 steps. h on the wire = SINGLE fp16 plane (16 MB/step). ----
    float cstate = 0.f;
    const int  orow  = bh * ROWS + eb;
    const long obase = (long)orow * (SEQ * HID) + hb + ej;

    for (int t = 0; t < SEQ; ++t){
        const _Float16* hc = hbuf + (t & 1) * BH;

        h8 aH[8];
        const _Float16* Ap = hc + grow * HID + kb;
        #pragma unroll
        for (int i = 0; i < 8; ++i) aH[i] = ldh8_llc(Ap + i * 32);

        f4 z0 = {0.f,0.f,0.f,0.f}, z1 = {0.f,0.f,0.f,0.f};
        #pragma unroll
        for (int i = 0; i < 8; ++i){
            z0 = MFMA(aH[i], Bh0[i], z0); z0 = MFMA(aH[i], Bl0[i], z0);
            z1 = MFMA(aH[i], Bh1[i], z1); z1 = MFMA(aH[i], Bl1[i], z1);
        }
        {
            int r0 = mt * 16 + ((lane >> 4) << 2);
            #pragma unroll
            for (int r = 0; r < 4; ++r){
                scr[ks][r0 + r][bcol]      = z0[r];
                scr[ks][r0 + r][16 + bcol] = z1[r];
            }
        }
        __syncthreads();                 // sync 1: scr exchange

        if (wave < 4){
            float zf = gx0 + scr[0][eb][ 0+ej] + scr[1][eb][ 0+ej] + scr[2][eb][ 0+ej] + scr[3][eb][ 0+ej];
            float zi = gx1 + scr[0][eb][ 8+ej] + scr[1][eb][ 8+ej] + scr[2][eb][ 8+ej] + scr[3][eb][ 8+ej];
            float zo = gx2 + scr[0][eb][16+ej] + scr[1][eb][16+ej] + scr[2][eb][16+ej] + scr[3][eb][16+ej];
            float zc = gx3 + scr[0][eb][24+ej] + scr[1][eb][24+ej] + scr[2][eb][24+ej] + scr[3][eb][24+ej];
            float f  = fsig(zf);
            float ii = fsig(zi);
            float o  = fsig(zo);
            float ch = ftanh(zc);
            cstate   = f * cstate + ii * ch;
            float hv = o * ftanh(cstate);

            if (t < SEQ - 1){
                _Float16* hn = hbuf + ((t + 1) & 1) * BH;
                _Float16 hhi = (_Float16)hv;
                unsigned uhi = (unsigned short)__builtin_bit_cast(unsigned short, hhi);
                unsigned phi = (unsigned)__shfl_xor((int)uhi, 1);
                if (!(ej & 1)){          // even col: store packed dword (this + partner)
                    int widx = (orow * HID + hb + ej) >> 1;
                    __hip_atomic_store((unsigned*)hn + widx, uhi | (phi << 16),
                                       __ATOMIC_RELAXED, __HIP_MEMORY_SCOPE_AGENT);
                }
            }
            out[obase + (long)t * HID] = hv;   // plain store: off the critical chain
        }
        __syncthreads();                 // sync 2: drains vmcnt for every wave
                                         // => h stores LLC-acked before arrive

        if (t < SEQ - 1){
            const unsigned tgt = (unsigned)(t + 1);
            if (wave == 0){
                // Arrive: own member line.
                if (lane == 0)
                    __hip_atomic_store(myMem, tgt, __ATOMIC_RELAXED, __HIP_MEMORY_SCOPE_AGENT);
                // Combine: 8 combiners/half each poll 16 member lines (single-reader lines).
                if (isComb){
                    const unsigned* mp = flags +
                        ((unsigned)((((mIdx + (lane & 15)) << 1) | bh)) << 4);
                    for (;;){
                        unsigned v = (lane < 16)
                            ? __hip_atomic_load(mp, __ATOMIC_RELAXED, __HIP_MEMORY_SCOPE_AGENT)
                            : ~0u;
                        if (__all((int)(v >= tgt))) break;
                        __builtin_amdgcn_s_sleep(1);
                    }
                    if (lane == 0)
                        __hip_atomic_store(flags + 4096 + ((unsigned)((bh << 3) + (mIdx >> 4)) << 5),
                                           tgt, __ATOMIC_RELAXED, __HIP_MEMORY_SCOPE_AGENT);
                }
                // Release-wait: poll only this half's 8 group lines.
                {
                    const unsigned* gp = flags + 4096 + ((unsigned)((bh << 3) + (lane & 7)) << 5);
                    for (;;){
                        unsigned v = (lane < 8)
                            ? __hip_atomic_load(gp, __ATOMIC_RELAXED, __HIP_MEMORY_SCOPE_AGENT)
                            : ~0u;
                        if (__all((int)(v >= tgt))) break;
                        __builtin_amdgcn_s_sleep(1);
                    }
                }
            }
            __syncthreads();             // sync 3: release the WG
        }
    }
}

extern "C" void kernel_launch(void* const* d_in, const int* in_sizes, int n_in,
                              void* d_out, int out_size, void* d_ws, size_t ws_size,
                              hipStream_t stream)
{
    const float* x  = (const float*)d_in[0];
    const float* wf = (const float*)d_in[1];
    const float* wi = (const float*)d_in[2];
    const float* wo = (const float*)d_in[3];
    const float* wc = (const float*)d_in[4];
    const float* uf = (const float*)d_in[5];
    const float* ui = (const float*)d_in[6];
    const float* uo = (const float*)d_in[7];
    const float* uc = (const float*)d_in[8];
    const float* bf = (const float*)d_in[9];
    const float* bi = (const float*)d_in[10];
    const float* bo = (const float*)d_in[11];
    const float* bc = (const float*)d_in[12];
    float* out = (float*)d_out;

    unsigned*  flags = (unsigned*)d_ws;                       // member+group flags, 32 KB
    _Float16*  hbuf  = (_Float16*)((char*)d_ws + 32768);      // h ping-pong, single plane

    // zero flags + both h ping-pong buffers; h0 = 0, epoch 0 == "h(0) ready"
    // footprint 32768 + 2*BH*2 = 294,912 B — strictly smaller than the proven 557,056.
    hipMemsetAsync(d_ws, 0, 32768 + (size_t)2 * BH * sizeof(_Float16), stream);

    void* args[] = { &x, &wf, &wi, &wo, &wc, &uf, &ui, &uo, &uc,
                     &bf, &bi, &bo, &bc, &out, &flags, &hbuf };
    hipLaunchCooperativeKernel((void*)lstm_kernel, dim3(NWG), dim3(BLK), args, 0, stream);
}